// Round 25
// baseline (87.570 us; speedup 1.0000x reference)
//
#include <hip/hip_runtime.h>
#include <hip/hip_bf16.h>

#define B_   32
#define L_   2048
#define CIN  256
#define HID  512
#define TL   16
#define TPT  16                    // tiles per block = 256 rows
#define NGRP 256                   // 256-row groups
#define NBLK (NGRP * 4)            // x4 col-quarters = 1024 blocks = 4/CU

// 2*log2(e): baked into Wc/bc so the gemm output feeds exp2 directly.
#define TANH_SCALE 2.885390081777927

typedef __bf16 bf16_t;
typedef __bf16 bf16x8 __attribute__((ext_vector_type(8)));
typedef __bf16 bf16x4 __attribute__((ext_vector_type(4)));
typedef float  f32x4  __attribute__((ext_vector_type(4)));

// LDS map (48 KB):
//   A dbuf @0:      buf*16384 + pipe*8192 + row*512 (swizzled rows)
//   TY dbuf @32768: buf*8192 + wq*1536 + cj*768 + l15*48 + l4*8  (<=2-way)
#define APIPE  8192u
#define ABUF   16384u
#define TY_OFF 32768u

// ---------------------------------------------------------------------------
// Kernel 1: compose Wc = TANH_SCALE * (W2 @ W1) (fp32 -> bf16),
//           bc = TANH_SCALE * (W2 @ b1 + b2).   (R21-proven shape; bc via
//           wave-0 parallel reduction; 16 loads in flight in the main loop)
// ---------------------------------------------------------------------------
__global__ void compose_kernel(const float* __restrict__ W1, const float* __restrict__ W2,
                               const float* __restrict__ b1, const float* __restrict__ b2,
                               bf16_t* __restrict__ Wc, float* __restrict__ bc)
{
    const int g = blockIdx.x;            // 512
    const int c = threadIdx.x;           // 256
    const float* w2row = W2 + (size_t)g * HID;
    float s[8] = {0.f, 0.f, 0.f, 0.f, 0.f, 0.f, 0.f, 0.f};
#pragma unroll 2
    for (int h = 0; h < HID; h += 8) {
#pragma unroll
        for (int k = 0; k < 8; ++k)
            s[k] = fmaf(w2row[h + k], W1[(size_t)(h + k) * CIN + c], s[k]);
    }
    float tot = ((s[0] + s[1]) + (s[2] + s[3])) + ((s[4] + s[5]) + (s[6] + s[7]));
    Wc[(size_t)g * CIN + c] = (bf16_t)(tot * (float)TANH_SCALE);
    if (c < 64) {                        // wave 0: parallel bc reduction
        float t = 0.f;
        for (int h = c; h < HID; h += 64)
            t = fmaf(w2row[h], b1[h], t);
#pragma unroll
        for (int off = 32; off >= 1; off >>= 1)
            t += __shfl_xor(t, off);
        if (c == 0) bc[g] = (t + b2[g]) * (float)TANH_SCALE;
    }
}

// ---------------------------------------------------------------------------
// Kernel 2: fused GEMM + tanh-pair-product + row-reduction (R24, unchanged:
// pipe-split ratio-2 gemm, XCD pairing, A dbuf + T14 prefetch, TY dbuf,
// atomicAdd epilogue into d_out). 1024 blocks x 512 thr. W reloads from
// L1/L2 by compiler choice (R22: pinning costs more occupancy than it saves).
// ---------------------------------------------------------------------------
__global__ __launch_bounds__(512, 4)
void fused_kernel(const float* __restrict__ x, const float* __restrict__ y,
                  const bf16_t* __restrict__ Wc, const float* __restrict__ bc,
                  float* __restrict__ out)
{
    __shared__ char U[49152];

    const int tid  = threadIdx.x;
    const int lane = tid & 63;
    const int wv   = tid >> 6;           // wave 0..7
    const int l15  = lane & 15;
    const int l4   = lane >> 4;

    // XCD-pairing decode: d%8 == grp%8 for all 4 q's of a grp (bijective)
    const int d    = blockIdx.x;
    const int grp  = (d & 7) + 8 * (d >> 5);
    const int q    = (d >> 3) & 3;

    const int pipe = wv >> 2;            // 0 = x-waves, 1 = y-waves
    const int wq   = wv & 3;
    const int gc0  = q * 128 + wq * 32;  // this wave's output-col base

    // --- weight fragments (compiler keeps or reloads from L1/L2 per tile)
    bf16x8 wreg[8][2];
#pragma unroll
    for (int kk = 0; kk < 8; ++kk)
#pragma unroll
        for (int cj = 0; cj < 2; ++cj)
            wreg[kk][cj] = *reinterpret_cast<const bf16x8*>(
                Wc + (size_t)(gc0 + cj * 16 + l15) * CIN + kk * 32 + l4 * 8);

    // bias fragments (scaled)
    f32x4 bcv[2];
#pragma unroll
    for (int cj = 0; cj < 2; ++cj) {
        float4 t4 = *reinterpret_cast<const float4*>(bc + gc0 + cj * 16 + l4 * 4);
        bcv[cj] = (f32x4){t4.x, t4.y, t4.z, t4.w};
    }

    // staging identity: threads 0-255 stage x, 256-511 stage y; 16 thr/row
    const int sp = tid >> 8;
    const int t8 = tid & 255;
    const int sr = t8 >> 4;              // row 0..15
    const int sq = t8 & 15;              // float4 slot
    const unsigned sswz = (unsigned)((sr & 15) << 4);
    const unsigned soff = (unsigned)(sp * APIPE + sr * 512);
    const float* sptr = (sp ? y : x) + ((size_t)grp * (TPT * TL) + sr) * CIN;

    float4 v[4];
    auto sload = [&](const float* rowbase) {
        const float4* s4 = reinterpret_cast<const float4*>(rowbase);
#pragma unroll
        for (int c = 0; c < 4; ++c) v[c] = s4[sq + 16 * c];
    };
    auto swrite = [&](int buf) {
        char* p = U + (unsigned)(buf * ABUF) + soff;
#pragma unroll
        for (int c = 0; c < 4; ++c) {
            const int f = sq + 16 * c;
            bf16x4 h;
            h[0] = (bf16_t)v[c].x; h[1] = (bf16_t)v[c].y;
            h[2] = (bf16_t)v[c].z; h[3] = (bf16_t)v[c].w;
            *reinterpret_cast<bf16x4*>(p + (((unsigned)(8 * f)) ^ sswz)) = h;
        }
    };

    // A fragment address (own pipe); per-kk addr = base ^ (kk<<6)
    const unsigned abase = (pipe ? APIPE : 0u) +
        (unsigned)(l15 * 512) + (((unsigned)(l4 * 16)) ^ ((unsigned)(l15 << 4)));
    // TY slot (dbuf handled by +buf*8192)
    const unsigned tyb = TY_OFF + (unsigned)(wq * 1536 + l15 * 48 + l4 * 8);

    f32x4 psum[2];
    psum[0] = (f32x4){0.f, 0.f, 0.f, 0.f};
    psum[1] = (f32x4){0.f, 0.f, 0.f, 0.f};

    // prologue: stage tile 0 into buf 0
    sload(sptr);
    swrite(0);
    __syncthreads();

    for (int t = 0; t < TPT; ++t) {
        const bool pf = (t + 1 < TPT);
        const int cur = t & 1;
        if (pf) {                        // issue tile t+1 loads early (T14)
            sptr += TL * CIN;
            sload(sptr);
        }

        // ---- gemm own pipe: 1 A-read : 2 MFMA
        f32x4 acc0 = bcv[0], acc1 = bcv[1];
        const unsigned ab = abase + (unsigned)(cur * ABUF);
        __builtin_amdgcn_s_setprio(1);
#pragma unroll
        for (int kk = 0; kk < 8; ++kk) {
            bf16x8 a = *reinterpret_cast<const bf16x8*>(U + (ab ^ (unsigned)(kk << 6)));
            acc0 = __builtin_amdgcn_mfma_f32_16x16x32_bf16(wreg[kk][0], a, acc0, 0, 0, 0);
            acc1 = __builtin_amdgcn_mfma_f32_16x16x32_bf16(wreg[kk][1], a, acc1, 0, 0, 0);
        }
        __builtin_amdgcn_s_setprio(0);

        // ---- tanh own pipe (scale baked in): t = 1 - 2/(exp2(a)+1);
        // no clamps: exp2 saturates to inf/0 -> tanh saturates to +-1.
#pragma unroll
        for (int r2 = 0; r2 < 4; ++r2) {
            acc0[r2] = fmaf(-2.0f, __builtin_amdgcn_rcpf(exp2f(acc0[r2]) + 1.0f), 1.0f);
            acc1[r2] = fmaf(-2.0f, __builtin_amdgcn_rcpf(exp2f(acc1[r2]) + 1.0f), 1.0f);
        }

        if (pipe) {                      // y-waves: publish tanh as bf16
            bf16x4 t0, t1;
#pragma unroll
            for (int r2 = 0; r2 < 4; ++r2) { t0[r2] = (bf16_t)acc0[r2]; t1[r2] = (bf16_t)acc1[r2]; }
            *reinterpret_cast<bf16x4*>(U + tyb + (unsigned)(cur * 8192))        = t0;
            *reinterpret_cast<bf16x4*>(U + tyb + (unsigned)(cur * 8192) + 768u) = t1;
        }

        if (pf) swrite(cur ^ 1);         // A(t+1) into the idle buffer

        __syncthreads();                 // publish TY[cur] + A[cur^1]

        if (!pipe) {                     // x-waves: product into psum
            bf16x4 o0 = *reinterpret_cast<const bf16x4*>(U + tyb + (unsigned)(cur * 8192));
            bf16x4 o1 = *reinterpret_cast<const bf16x4*>(U + tyb + (unsigned)(cur * 8192) + 768u);
#pragma unroll
            for (int r2 = 0; r2 < 4; ++r2) {
                psum[0][r2] = fmaf(acc0[r2], (float)o0[r2], psum[0][r2]);
                psum[1][r2] = fmaf(acc1[r2], (float)o1[r2], psum[1][r2]);
            }
        }
    }

    // x-waves: reduce over the 16 row-lanes, then atomicAdd into out
    if (!pipe) {
#pragma unroll
        for (int cj = 0; cj < 2; ++cj)
#pragma unroll
            for (int r2 = 0; r2 < 4; ++r2) {
                float s = psum[cj][r2];
                s += __shfl_xor(s, 1);
                s += __shfl_xor(s, 2);
                s += __shfl_xor(s, 4);
                s += __shfl_xor(s, 8);
                psum[cj][r2] = s;
            }
        if (l15 == 0) {
            const int b = grp >> 3;      // batch = grp/8
            float* ob = out + (size_t)b * HID + gc0 + l4 * 4;
#pragma unroll
            for (int cj = 0; cj < 2; ++cj)
#pragma unroll
                for (int r2 = 0; r2 < 4; ++r2)
                    atomicAdd(ob + cj * 16 + r2, psum[cj][r2]);
        }
    }
}

extern "C" void kernel_launch(void* const* d_in, const int* in_sizes, int n_in,
                              void* d_out, int out_size, void* d_ws, size_t ws_size,
                              hipStream_t stream)
{
    const float* x  = (const float*)d_in[0];
    const float* y  = (const float*)d_in[1];
    const float* W1 = (const float*)d_in[2];
    const float* b1 = (const float*)d_in[3];
    const float* W2 = (const float*)d_in[4];
    const float* b2 = (const float*)d_in[5];
    float* out = (float*)d_out;

    char* ws = (char*)d_ws;
    bf16_t* Wc = (bf16_t*)ws;                    // 256 KB
    float*  bc = (float*)(ws + (256 << 10));     // 2 KB

    // DMA fill instead of a zero-kernel launch (graph-capturable)
    hipMemsetAsync(out, 0, (size_t)out_size * sizeof(float), stream);
    hipLaunchKernelGGL(compose_kernel, dim3(HID), dim3(CIN), 0, stream, W1, W2, b1, b2, Wc, bc);
    hipLaunchKernelGGL(fused_kernel, dim3(NBLK), dim3(512), 0, stream, x, y, Wc, bc, out);
}